// Round 1
// baseline (534.811 us; speedup 1.0000x reference)
//
#include <hip/hip_runtime.h>
#include <hip/hip_bf16.h>
#include <cstdint>
#include <type_traits>

typedef __attribute__((ext_vector_type(8))) short short8;
typedef __attribute__((ext_vector_type(4))) float floatx4;

constexpr int S_LEN = 2048;
constexpr int QKV_N = 3072;   // q[0..2047] | k[2048..2559] | v[2560..3071]
constexpr float ATTN_SCALE = 0.08838834764831845f;  // 128^-0.5
constexpr float LOG2E = 1.4426950408889634f;

// ---------------------------------------------------------------- async G->LDS
__device__ __forceinline__ void gl_lds16(const void* gp, void* lp) {
  __builtin_amdgcn_global_load_lds(
      (__attribute__((address_space(1))) void*)(uintptr_t)gp,
      (__attribute__((address_space(3))) void*)lp,
      16, 0, 0);
}

// ---------------------------------------------------------------- fp32 -> bf16
__global__ void cvt_bf16_kernel(const float* __restrict__ src,
                                __hip_bfloat16* __restrict__ dst, int n4) {
  int i = blockIdx.x * blockDim.x + threadIdx.x;
  if (i >= n4) return;
  float4 f = reinterpret_cast<const float4*>(src)[i];
  union { unsigned long long u64; __hip_bfloat16 h[4]; } u;
  u.h[0] = __float2bfloat16(f.x);
  u.h[1] = __float2bfloat16(f.y);
  u.h[2] = __float2bfloat16(f.z);
  u.h[3] = __float2bfloat16(f.w);
  reinterpret_cast<unsigned long long*>(dst)[i] = u.u64;
}

// ------------------------------------------------- fp32 [K][N] -> bf16 [N][K]
__global__ void transpose_bf16_kernel(const float* __restrict__ src,
                                      __hip_bfloat16* __restrict__ dst,
                                      int K, int N) {
  __shared__ float tile[32][33];
  int n0 = blockIdx.x * 32, k0 = blockIdx.y * 32;
  int tx = threadIdx.x, ty = threadIdx.y;   // (32, 8)
#pragma unroll
  for (int i = ty; i < 32; i += 8)
    tile[i][tx] = src[(size_t)(k0 + i) * N + n0 + tx];
  __syncthreads();
#pragma unroll
  for (int i = ty; i < 32; i += 8)
    dst[(size_t)(n0 + i) * K + k0 + tx] = __float2bfloat16(tile[tx][i]);
}

// --------------------------------------------------------------------- GEMM
// C[M][N] = A[M][K] * Bt[N][K]^T ; bf16 in, fp32 acc, OutT out.
// 128x128 tile, 4 waves (2x2), BK=64, global_load_lds staging into
// chunk-transposed LDS: chunk = kchunk*128 + row (kchunk = k/8).
template <typename OutT>
__global__ __launch_bounds__(256, 2) void gemm_bt_kernel(
    const __hip_bfloat16* __restrict__ A,
    const __hip_bfloat16* __restrict__ Bt,
    OutT* __restrict__ C, int N, int K) {
  __shared__ __align__(16) __hip_bfloat16 lds[2 * 128 * 64];
  const int tid = threadIdx.x;
  const int wave = tid >> 6, lane = tid & 63;
  const int quad = lane >> 4, l15 = lane & 15;
  const int wm = wave >> 1, wn = wave & 1;
  const int m0 = blockIdx.y * 128, n0 = blockIdx.x * 128;

  floatx4 acc[4][4] = {};

  const __hip_bfloat16* Ab = A + (size_t)m0 * K;
  const __hip_bfloat16* Bb = Bt + (size_t)n0 * K;
  const int i0 = wave * 4;

  for (int k0 = 0; k0 < K; k0 += 64) {
#pragma unroll
    for (int j = 0; j < 4; ++j) {
      const int i = i0 + j;             // instr 0..15, 64 contiguous chunks each
      const int kchunk = i >> 1;
      const int row = ((i & 1) << 6) | lane;
      gl_lds16(Ab + (size_t)row * K + (k0 + kchunk * 8), &lds[i * 512]);
      gl_lds16(Bb + (size_t)row * K + (k0 + kchunk * 8), &lds[8192 + i * 512]);
    }
    __syncthreads();   // drains vmcnt (compiler-inserted) -> LDS tiles valid
#pragma unroll
    for (int kk = 0; kk < 2; ++kk) {
      short8 a[4], b[4];
#pragma unroll
      for (int mi = 0; mi < 4; ++mi)
        a[mi] = *(const short8*)&lds[((((kk << 2) | quad) * 128) + wm * 64 + mi * 16 + l15) * 8];
#pragma unroll
      for (int ni = 0; ni < 4; ++ni)
        b[ni] = *(const short8*)&lds[8192 + ((((kk << 2) | quad) * 128) + wn * 64 + ni * 16 + l15) * 8];
#pragma unroll
      for (int mi = 0; mi < 4; ++mi)
#pragma unroll
        for (int ni = 0; ni < 4; ++ni)
          acc[mi][ni] = __builtin_amdgcn_mfma_f32_16x16x32_bf16(a[mi], b[ni], acc[mi][ni], 0, 0, 0);
    }
    __syncthreads();
  }

#pragma unroll
  for (int mi = 0; mi < 4; ++mi)
#pragma unroll
    for (int ni = 0; ni < 4; ++ni)
#pragma unroll
      for (int r = 0; r < 4; ++r) {
        int row = m0 + wm * 64 + mi * 16 + quad * 4 + r;  // C/D: row = quad*4+reg
        int col = n0 + wn * 64 + ni * 16 + l15;           //      col = lane&15
        float v = acc[mi][ni][r];
        if constexpr (std::is_same<OutT, float>::value)
          C[(size_t)row * N + col] = v;
        else
          C[(size_t)row * N + col] = __float2bfloat16(v);
      }
}

// --------------------------------------------------------------------- RoPE
// In-place on qkv bf16: heads 0..15 = q, 16..19 = k (col = head*128).
// out[d]    = x[d]*cos[d>>1]      - x[d+64]*sin[d>>1]
// out[d+64] = x[d+64]*cos[32+d>>1] + x[d]*sin[32+d>>1]
__global__ void rope_kernel(__hip_bfloat16* __restrict__ qkv,
                            const float* __restrict__ cosb,
                            const float* __restrict__ sinb) {
  int t = blockIdx.x * blockDim.x + threadIdx.x;  // 4096*20*64 threads exactly
  int d = t & 63;
  int head = (t >> 6) % 20;
  int row = t / 1280;
  int s = row & (S_LEN - 1);
  size_t base = (size_t)row * QKV_N + head * 128 + d;
  float x0 = __bfloat162float(qkv[base]);
  float x1 = __bfloat162float(qkv[base + 64]);
  int ci = s * 64 + (d >> 1);
  float c0 = cosb[ci], s0 = sinb[ci];
  float c1 = cosb[ci + 32], s1 = sinb[ci + 32];
  qkv[base]      = __float2bfloat16(x0 * c0 - x1 * s0);
  qkv[base + 64] = __float2bfloat16(x1 * c1 + x0 * s1);
}

// ---------------------------------------------------------------- attention
// grid (32 q-tiles, 32 bh), 256 thr. Wave w owns q rows qt*64+w*16..+15.
__global__ __launch_bounds__(256, 2) void attn_kernel(
    const __hip_bfloat16* __restrict__ qkv,   // [4096][3072]
    __hip_bfloat16* __restrict__ aout) {      // [4096][2048]
  const int qt = gridDim.x - 1 - blockIdx.x;  // heavy tiles dispatch first
  const int bh = blockIdx.y;
  const int b = bh >> 4, h = bh & 15;
  const int kvh = h >> 2;                     // GQA: group of 4

  __shared__ __align__(16) __hip_bfloat16 Klds[64 * 136];   // [kv][d], pad 8
  __shared__ __align__(16) __hip_bfloat16 Vlds[128 * 72];   // [d][kv], pad 8
  __shared__ __align__(16) __hip_bfloat16 Plds[4 * 16 * 72];

  const int tid = threadIdx.x;
  const int wave = tid >> 6, lane = tid & 63;
  const int quad = lane >> 4, l15 = lane & 15;

  // Q fragments stay in registers across the whole KV loop (A-operand layout:
  // m = lane&15, k = quad*8+j within each 32-chunk).
  const __hip_bfloat16* qbase = qkv + (size_t)(b * S_LEN + qt * 64) * QKV_N + h * 128;
  short8 qfrag[4];
#pragma unroll
  for (int kc = 0; kc < 4; ++kc)
    qfrag[kc] = *(const short8*)(qbase + (size_t)(wave * 16 + l15) * QKV_N + kc * 32 + quad * 8);

  float m_r[4], l_r[4];
  floatx4 o[8] = {};
#pragma unroll
  for (int r = 0; r < 4; ++r) { m_r[r] = -1e30f; l_r[r] = 0.f; }

  __hip_bfloat16* pw = &Plds[wave * 16 * 72];

  for (int kt = 0; kt <= qt; ++kt) {
    const __hip_bfloat16* kbase = qkv + (size_t)(b * S_LEN + kt * 64) * QKV_N + 2048 + kvh * 128;
    const __hip_bfloat16* vbase = kbase + 512;
    // K tile: 1024 16B chunks, row layout [kv][136]
#pragma unroll
    for (int j = 0; j < 4; ++j) {
      int c = tid + 256 * j;
      int kv = c >> 4, d0 = (c & 15) * 8;
      *(short8*)&Klds[kv * 136 + d0] = *(const short8*)(kbase + (size_t)kv * QKV_N + d0);
    }
    // V tile transposed: pair of kv rows -> 8 packed 4B writes (conflict-free)
#pragma unroll
    for (int j = 0; j < 2; ++j) {
      int p = tid + 256 * j;
      int kvp = (p & 31) * 2;
      int d0 = (p >> 5) * 8;
      short8 r0 = *(const short8*)(vbase + (size_t)kvp * QKV_N + d0);
      short8 r1 = *(const short8*)(vbase + (size_t)(kvp + 1) * QKV_N + d0);
#pragma unroll
      for (int e = 0; e < 8; ++e) {
        unsigned int pk = (unsigned short)r0[e] | ((unsigned int)(unsigned short)r1[e] << 16);
        *(unsigned int*)&Vlds[(d0 + e) * 72 + kvp] = pk;
      }
    }
    __syncthreads();

    // scores S = Q K^T  (B-operand: n = kv col = lane&15, k = d, contiguous)
    floatx4 sc[4] = {};
#pragma unroll
    for (int ni = 0; ni < 4; ++ni)
#pragma unroll
      for (int kc = 0; kc < 4; ++kc) {
        short8 bf = *(const short8*)&Klds[(ni * 16 + l15) * 136 + kc * 32 + quad * 8];
        sc[ni] = __builtin_amdgcn_mfma_f32_16x16x32_bf16(qfrag[kc], bf, sc[ni], 0, 0, 0);
      }

    const int qrow = qt * 64 + wave * 16 + quad * 4;
    if (kt == qt) {
#pragma unroll
      for (int ni = 0; ni < 4; ++ni) {
        int kvcol = kt * 64 + ni * 16 + l15;
#pragma unroll
        for (int r = 0; r < 4; ++r) {
          float s = sc[ni][r] * ATTN_SCALE;
          sc[ni][r] = (kvcol > qrow + r) ? -1e30f : s;
        }
      }
    } else {
#pragma unroll
      for (int ni = 0; ni < 4; ++ni)
#pragma unroll
        for (int r = 0; r < 4; ++r) sc[ni][r] *= ATTN_SCALE;
    }

    // online softmax: rows live in 16-lane groups (quad), one row per reg
    float alpha[4];
#pragma unroll
    for (int r = 0; r < 4; ++r) {
      float v = fmaxf(fmaxf(sc[0][r], sc[1][r]), fmaxf(sc[2][r], sc[3][r]));
      v = fmaxf(v, __shfl_xor(v, 1, 64));
      v = fmaxf(v, __shfl_xor(v, 2, 64));
      v = fmaxf(v, __shfl_xor(v, 4, 64));
      v = fmaxf(v, __shfl_xor(v, 8, 64));
      float mnew = fmaxf(m_r[r], v);
      alpha[r] = exp2f((m_r[r] - mnew) * LOG2E);
      m_r[r] = mnew;
      float acc = 0.f;
#pragma unroll
      for (int ni = 0; ni < 4; ++ni) {
        float p = exp2f((sc[ni][r] - mnew) * LOG2E);
        sc[ni][r] = p;
        acc += p;
      }
      acc += __shfl_xor(acc, 1, 64);
      acc += __shfl_xor(acc, 2, 64);
      acc += __shfl_xor(acc, 4, 64);
      acc += __shfl_xor(acc, 8, 64);
      l_r[r] = l_r[r] * alpha[r] + acc;
      // P round-trip: write C/D layout, read back in A-operand layout
#pragma unroll
      for (int ni = 0; ni < 4; ++ni)
        pw[(quad * 4 + r) * 72 + ni * 16 + l15] = __float2bfloat16(sc[ni][r]);
    }

#pragma unroll
    for (int nc = 0; nc < 8; ++nc)
#pragma unroll
      for (int r = 0; r < 4; ++r) o[nc][r] *= alpha[r];

    // O += P V   (A = P from LDS round-trip; B = V^T tile, contiguous)
#pragma unroll
    for (int kk2 = 0; kk2 < 2; ++kk2) {
      short8 pa = *(const short8*)&pw[l15 * 72 + kk2 * 32 + quad * 8];
#pragma unroll
      for (int nc = 0; nc < 8; ++nc) {
        short8 vb = *(const short8*)&Vlds[(nc * 16 + l15) * 72 + kk2 * 32 + quad * 8];
        o[nc] = __builtin_amdgcn_mfma_f32_16x16x32_bf16(pa, vb, o[nc], 0, 0, 0);
      }
    }
    __syncthreads();
  }

  float inv[4];
#pragma unroll
  for (int r = 0; r < 4; ++r) inv[r] = 1.0f / l_r[r];
  const size_t orow0 = (size_t)(b * S_LEN + qt * 64 + wave * 16 + quad * 4);
#pragma unroll
  for (int nc = 0; nc < 8; ++nc)
#pragma unroll
    for (int r = 0; r < 4; ++r)
      aout[(orow0 + r) * 2048 + h * 128 + nc * 16 + l15] =
          __float2bfloat16(o[nc][r] * inv[r]);
}

// -------------------------------------------------------------------- launch
extern "C" void kernel_launch(void* const* d_in, const int* in_sizes, int n_in,
                              void* d_out, int out_size, void* d_ws, size_t ws_size,
                              hipStream_t stream) {
  const float* x    = (const float*)d_in[0];
  const float* cosb = (const float*)d_in[1];
  const float* sinb = (const float*)d_in[2];
  // d_in[3] = mask (causal, implemented analytically)
  const float* Wq = (const float*)d_in[4];
  const float* Wk = (const float*)d_in[5];
  const float* Wv = (const float*)d_in[6];
  const float* Wo = (const float*)d_in[7];
  float* out = (float*)d_out;

  char* ws = (char*)d_ws;
  __hip_bfloat16* xb    = (__hip_bfloat16*)(ws);                       // 16 MB
  __hip_bfloat16* wqkvt = (__hip_bfloat16*)(ws + 16777216);            // 12 MB  [3072][2048]
  __hip_bfloat16* wot   = (__hip_bfloat16*)(ws + 29360128);            // 8 MB   [2048][2048]
  __hip_bfloat16* qkv   = (__hip_bfloat16*)(ws + 37748736);            // 24 MB  [4096][3072]
  __hip_bfloat16* aout  = (__hip_bfloat16*)(ws + 62914560);            // 16 MB  [4096][2048]

  dim3 tb(32, 8);
  cvt_bf16_kernel<<<8192, 256, 0, stream>>>(x, xb, 2097152);
  transpose_bf16_kernel<<<dim3(64, 64), tb, 0, stream>>>(Wq, wqkvt, 2048, 2048);
  transpose_bf16_kernel<<<dim3(16, 64), tb, 0, stream>>>(Wk, wqkvt + 2048 * 2048, 2048, 512);
  transpose_bf16_kernel<<<dim3(16, 64), tb, 0, stream>>>(Wv, wqkvt + 2560 * 2048, 2048, 512);
  transpose_bf16_kernel<<<dim3(64, 64), tb, 0, stream>>>(Wo, wot, 2048, 2048);

  gemm_bt_kernel<__hip_bfloat16><<<dim3(24, 32), 256, 0, stream>>>(xb, wqkvt, qkv, 3072, 2048);
  rope_kernel<<<20480, 256, 0, stream>>>(qkv, cosb, sinb);
  attn_kernel<<<dim3(32, 32), 256, 0, stream>>>(qkv, aout);
  gemm_bt_kernel<float><<<dim3(16, 32), 256, 0, stream>>>(aout, wot, out, 2048, 2048);
}

// Round 2
// 531.347 us; speedup vs baseline: 1.0065x; 1.0065x over previous
//
#include <hip/hip_runtime.h>
#include <hip/hip_bf16.h>
#include <cstdint>
#include <type_traits>

typedef __attribute__((ext_vector_type(8))) short short8;
typedef __attribute__((ext_vector_type(4))) float floatx4;

constexpr int S_LEN = 2048;
constexpr int QKV_N = 3072;   // q[0..2047] | k[2048..2559] | v[2560..3071]
constexpr float ATTN_SCALE = 0.08838834764831845f;  // 128^-0.5
constexpr float LOG2E = 1.4426950408889634f;

// ---------------------------------------------------------------- async G->LDS
__device__ __forceinline__ void gl_lds16(const void* gp, void* lp) {
  __builtin_amdgcn_global_load_lds(
      (__attribute__((address_space(1))) void*)(uintptr_t)gp,
      (__attribute__((address_space(3))) void*)lp,
      16, 0, 0);
}

// ---------------------------------------------------------------- fp32 -> bf16
__global__ void cvt_bf16_kernel(const float* __restrict__ src,
                                __hip_bfloat16* __restrict__ dst, int n4) {
  int i = blockIdx.x * blockDim.x + threadIdx.x;
  if (i >= n4) return;
  float4 f = reinterpret_cast<const float4*>(src)[i];
  union { unsigned long long u64; __hip_bfloat16 h[4]; } u;
  u.h[0] = __float2bfloat16(f.x);
  u.h[1] = __float2bfloat16(f.y);
  u.h[2] = __float2bfloat16(f.z);
  u.h[3] = __float2bfloat16(f.w);
  reinterpret_cast<unsigned long long*>(dst)[i] = u.u64;
}

// ------------------------------------------------- fp32 [K][N] -> bf16 [N][K]
__global__ void transpose_bf16_kernel(const float* __restrict__ src,
                                      __hip_bfloat16* __restrict__ dst,
                                      int K, int N) {
  __shared__ float tile[32][33];
  int n0 = blockIdx.x * 32, k0 = blockIdx.y * 32;
  int tx = threadIdx.x, ty = threadIdx.y;   // (32, 8)
#pragma unroll
  for (int i = ty; i < 32; i += 8)
    tile[i][tx] = src[(size_t)(k0 + i) * N + n0 + tx];
  __syncthreads();
#pragma unroll
  for (int i = ty; i < 32; i += 8)
    dst[(size_t)(n0 + i) * K + k0 + tx] = __float2bfloat16(tile[tx][i]);
}

// --------------------------------------------------------------------- GEMM
// C[M][N] = A[M][K] * Bt[N][K]^T ; bf16 in, fp32 acc, OutT out.
// 128x128 tile, 4 waves (2x2), BK=64, global_load_lds staging into
// chunk-transposed LDS: chunk = kchunk*128 + row (kchunk = k/8).
template <typename OutT>
__global__ __launch_bounds__(256, 2) void gemm_bt_kernel(
    const __hip_bfloat16* __restrict__ A,
    const __hip_bfloat16* __restrict__ Bt,
    OutT* __restrict__ C, int N, int K) {
  __shared__ __align__(16) __hip_bfloat16 lds[2 * 128 * 64];
  const int tid = threadIdx.x;
  const int wave = tid >> 6, lane = tid & 63;
  const int quad = lane >> 4, l15 = lane & 15;
  const int wm = wave >> 1, wn = wave & 1;
  const int m0 = blockIdx.y * 128, n0 = blockIdx.x * 128;

  floatx4 acc[4][4] = {};

  const __hip_bfloat16* Ab = A + (size_t)m0 * K;
  const __hip_bfloat16* Bb = Bt + (size_t)n0 * K;
  const int i0 = wave * 4;

  for (int k0 = 0; k0 < K; k0 += 64) {
#pragma unroll
    for (int j = 0; j < 4; ++j) {
      const int i = i0 + j;             // instr 0..15, 64 contiguous chunks each
      const int kchunk = i >> 1;
      const int row = ((i & 1) << 6) | lane;
      gl_lds16(Ab + (size_t)row * K + (k0 + kchunk * 8), &lds[i * 512]);
      gl_lds16(Bb + (size_t)row * K + (k0 + kchunk * 8), &lds[8192 + i * 512]);
    }
    __syncthreads();   // drains vmcnt (compiler-inserted) -> LDS tiles valid
#pragma unroll
    for (int kk = 0; kk < 2; ++kk) {
      short8 a[4], b[4];
#pragma unroll
      for (int mi = 0; mi < 4; ++mi)
        a[mi] = *(const short8*)&lds[((((kk << 2) | quad) * 128) + wm * 64 + mi * 16 + l15) * 8];
#pragma unroll
      for (int ni = 0; ni < 4; ++ni)
        b[ni] = *(const short8*)&lds[8192 + ((((kk << 2) | quad) * 128) + wn * 64 + ni * 16 + l15) * 8];
#pragma unroll
      for (int mi = 0; mi < 4; ++mi)
#pragma unroll
        for (int ni = 0; ni < 4; ++ni)
          acc[mi][ni] = __builtin_amdgcn_mfma_f32_16x16x32_bf16(a[mi], b[ni], acc[mi][ni], 0, 0, 0);
    }
    __syncthreads();
  }

#pragma unroll
  for (int mi = 0; mi < 4; ++mi)
#pragma unroll
    for (int ni = 0; ni < 4; ++ni)
#pragma unroll
      for (int r = 0; r < 4; ++r) {
        int row = m0 + wm * 64 + mi * 16 + quad * 4 + r;  // C/D: row = quad*4+reg
        int col = n0 + wn * 64 + ni * 16 + l15;           //      col = lane&15
        float v = acc[mi][ni][r];
        if constexpr (std::is_same<OutT, float>::value)
          C[(size_t)row * N + col] = v;
        else
          C[(size_t)row * N + col] = __float2bfloat16(v);
      }
}

// --------------------------------------------------------------------- RoPE
__global__ void rope_kernel(__hip_bfloat16* __restrict__ qkv,
                            const float* __restrict__ cosb,
                            const float* __restrict__ sinb) {
  int t = blockIdx.x * blockDim.x + threadIdx.x;  // 4096*20*64 threads exactly
  int d = t & 63;
  int head = (t >> 6) % 20;
  int row = t / 1280;
  int s = row & (S_LEN - 1);
  size_t base = (size_t)row * QKV_N + head * 128 + d;
  float x0 = __bfloat162float(qkv[base]);
  float x1 = __bfloat162float(qkv[base + 64]);
  int ci = s * 64 + (d >> 1);
  float c0 = cosb[ci], s0 = sinb[ci];
  float c1 = cosb[ci + 32], s1 = sinb[ci + 32];
  qkv[base]      = __float2bfloat16(x0 * c0 - x1 * s0);
  qkv[base + 64] = __float2bfloat16(x1 * c1 + x0 * s1);
}

// ---------------------------------------------------------------- attention
// grid (32 q-tiles, 32 bh), 256 thr. Wave w owns q rows qt*64+w*16..+15.
// K: double-buffered global_load_lds DMA, chunk-transposed (c = (d/8)*64+kv).
// V: register-prefetched one tile ahead, single LDS buffer [d][kv+8].
// Row-sums of P via ones-column MFMA (no sum shuffles).
__global__ __launch_bounds__(256, 2) void attn_kernel(
    const __hip_bfloat16* __restrict__ qkv,   // [4096][3072]
    __hip_bfloat16* __restrict__ aout) {      // [4096][2048]
  const int qt = gridDim.x - 1 - blockIdx.x;  // heavy tiles dispatch first
  const int bh = blockIdx.y;
  const int b = bh >> 4, h = bh & 15;
  const int kvh = h >> 2;                     // GQA: group of 4

  __shared__ __align__(16) __hip_bfloat16 Kbuf[2][1024 * 8];  // 2 x 16 KB
  __shared__ __align__(16) __hip_bfloat16 Vlds[128 * 72];     // [d][kv], pad 8
  __shared__ __align__(16) __hip_bfloat16 Plds[4 * 16 * 72];

  const int tid = threadIdx.x;
  const int wave = tid >> 6, lane = tid & 63;
  const int quad = lane >> 4, l15 = lane & 15;

  // Q fragments in registers for the whole KV loop (A-operand layout).
  const __hip_bfloat16* qbase = qkv + (size_t)(b * S_LEN + qt * 64) * QKV_N + h * 128;
  short8 qfrag[4];
#pragma unroll
  for (int kc = 0; kc < 4; ++kc)
    qfrag[kc] = *(const short8*)(qbase + (size_t)(wave * 16 + l15) * QKV_N + kc * 32 + quad * 8);

  const __hip_bfloat16* kvrow0 = qkv + (size_t)(b * S_LEN) * QKV_N + 2048 + kvh * 128;

  // ---- prologue: DMA K(0), prefetch V(0) into registers
  {
    const __hip_bfloat16* kb = kvrow0;
#pragma unroll
    for (int j = 0; j < 4; ++j) {
      int c = tid + 256 * j;               // chunk = (d/8)*64 + kv
      int kv = c & 63, dc = c >> 6;
      gl_lds16(kb + (size_t)kv * QKV_N + dc * 8, &Kbuf[0][c * 8]);
    }
  }
  short8 vcur[4], vnxt[4];
  {
    const __hip_bfloat16* vb = kvrow0 + 512;
#pragma unroll
    for (int j = 0; j < 2; ++j) {
      int p = tid + 256 * j;
      int kvp = (p & 31) * 2, d0 = (p >> 5) * 8;
      vcur[2 * j]     = *(const short8*)(vb + (size_t)kvp * QKV_N + d0);
      vcur[2 * j + 1] = *(const short8*)(vb + (size_t)(kvp + 1) * QKV_N + d0);
    }
  }

  float m_r[4];
  floatx4 o[8] = {};
  floatx4 o_l = {};     // running row-sum accumulator (ones-column MFMA)
#pragma unroll
  for (int r = 0; r < 4; ++r) m_r[r] = -1e30f;

  short8 onesb;
#pragma unroll
  for (int e = 0; e < 8; ++e) onesb[e] = (short)0x3F80;  // bf16 1.0

  __hip_bfloat16* pw = &Plds[wave * 16 * 72];

  for (int kt = 0; kt <= qt; ++kt) {
    const int cur = kt & 1;
    // V(kt): registers -> LDS transposed [d][kv+8] (conflict-free b32 writes)
#pragma unroll
    for (int j = 0; j < 2; ++j) {
      int p = tid + 256 * j;
      int kvp = (p & 31) * 2, d0 = (p >> 5) * 8;
      short8 r0 = vcur[2 * j], r1 = vcur[2 * j + 1];
#pragma unroll
      for (int e = 0; e < 8; ++e) {
        unsigned int pk = (unsigned short)r0[e] | ((unsigned int)(unsigned short)r1[e] << 16);
        *(unsigned int*)&Vlds[(d0 + e) * 72 + kvp] = pk;
      }
    }
    __syncthreads();   // A: K-DMA(kt) drained (vmcnt), V(kt) visible

    // prefetch next tile: K-DMA into other buffer, V into registers
    if (kt < qt) {
      const __hip_bfloat16* kb = kvrow0 + (size_t)(kt + 1) * 64 * QKV_N;
#pragma unroll
      for (int j = 0; j < 4; ++j) {
        int c = tid + 256 * j;
        int kv = c & 63, dc = c >> 6;
        gl_lds16(kb + (size_t)kv * QKV_N + dc * 8, &Kbuf[1 - cur][c * 8]);
      }
      const __hip_bfloat16* vb = kvrow0 + (size_t)(kt + 1) * 64 * QKV_N + 512;
#pragma unroll
      for (int j = 0; j < 2; ++j) {
        int p = tid + 256 * j;
        int kvp = (p & 31) * 2, d0 = (p >> 5) * 8;
        vnxt[2 * j]     = *(const short8*)(vb + (size_t)kvp * QKV_N + d0);
        vnxt[2 * j + 1] = *(const short8*)(vb + (size_t)(kvp + 1) * QKV_N + d0);
      }
    }

    // scores S = Q K^T  (B-frag from chunk-transposed Kbuf: conflict-free)
    floatx4 sc[4] = {};
#pragma unroll
    for (int ni = 0; ni < 4; ++ni)
#pragma unroll
      for (int kc = 0; kc < 4; ++kc) {
        short8 bf = *(const short8*)&Kbuf[cur][((kc * 4 + quad) * 64 + ni * 16 + l15) * 8];
        sc[ni] = __builtin_amdgcn_mfma_f32_16x16x32_bf16(qfrag[kc], bf, sc[ni], 0, 0, 0);
      }

    const int qrow = qt * 64 + wave * 16 + quad * 4;
    if (kt == qt) {
#pragma unroll
      for (int ni = 0; ni < 4; ++ni) {
        int kvcol = kt * 64 + ni * 16 + l15;
#pragma unroll
        for (int r = 0; r < 4; ++r) {
          float s = sc[ni][r] * ATTN_SCALE;
          sc[ni][r] = (kvcol > qrow + r) ? -1e30f : s;
        }
      }
    } else {
#pragma unroll
      for (int ni = 0; ni < 4; ++ni)
#pragma unroll
        for (int r = 0; r < 4; ++r) sc[ni][r] *= ATTN_SCALE;
    }

    // online softmax: row max via 16-lane shuffles; sums via ones-MFMA later
    float alpha[4];
#pragma unroll
    for (int r = 0; r < 4; ++r) {
      float v = fmaxf(fmaxf(sc[0][r], sc[1][r]), fmaxf(sc[2][r], sc[3][r]));
      v = fmaxf(v, __shfl_xor(v, 1, 64));
      v = fmaxf(v, __shfl_xor(v, 2, 64));
      v = fmaxf(v, __shfl_xor(v, 4, 64));
      v = fmaxf(v, __shfl_xor(v, 8, 64));
      float mnew = fmaxf(m_r[r], v);
      alpha[r] = exp2f((m_r[r] - mnew) * LOG2E);
      m_r[r] = mnew;
#pragma unroll
      for (int ni = 0; ni < 4; ++ni) {
        float p = exp2f((sc[ni][r] - mnew) * LOG2E);
        pw[(quad * 4 + r) * 72 + ni * 16 + l15] = __float2bfloat16(p);
      }
    }

#pragma unroll
    for (int nc = 0; nc < 8; ++nc)
#pragma unroll
      for (int r = 0; r < 4; ++r) o[nc][r] *= alpha[r];
#pragma unroll
    for (int r = 0; r < 4; ++r) o_l[r] *= alpha[r];

    // O += P V ; l += P 1   (A = P from LDS round-trip; B = V^T / ones)
#pragma unroll
    for (int kk2 = 0; kk2 < 2; ++kk2) {
      short8 pa = *(const short8*)&pw[l15 * 72 + kk2 * 32 + quad * 8];
#pragma unroll
      for (int nc = 0; nc < 8; ++nc) {
        short8 vb = *(const short8*)&Vlds[(nc * 16 + l15) * 72 + kk2 * 32 + quad * 8];
        o[nc] = __builtin_amdgcn_mfma_f32_16x16x32_bf16(pa, vb, o[nc], 0, 0, 0);
      }
      o_l = __builtin_amdgcn_mfma_f32_16x16x32_bf16(pa, onesb, o_l, 0, 0, 0);
    }
    __syncthreads();   // B: Vlds/Kbuf reads done before next iteration's writes

#pragma unroll
    for (int e = 0; e < 4; ++e) vcur[e] = vnxt[e];
  }

  float inv[4];
#pragma unroll
  for (int r = 0; r < 4; ++r) inv[r] = 1.0f / o_l[r];
  const size_t orow0 = (size_t)(b * S_LEN + qt * 64 + wave * 16 + quad * 4);
#pragma unroll
  for (int nc = 0; nc < 8; ++nc)
#pragma unroll
    for (int r = 0; r < 4; ++r)
      aout[(orow0 + r) * 2048 + h * 128 + nc * 16 + l15] =
          __float2bfloat16(o[nc][r] * inv[r]);
}

// -------------------------------------------------------------------- launch
extern "C" void kernel_launch(void* const* d_in, const int* in_sizes, int n_in,
                              void* d_out, int out_size, void* d_ws, size_t ws_size,
                              hipStream_t stream) {
  const float* x    = (const float*)d_in[0];
  const float* cosb = (const float*)d_in[1];
  const float* sinb = (const float*)d_in[2];
  // d_in[3] = mask (causal, implemented analytically)
  const float* Wq = (const float*)d_in[4];
  const float* Wk = (const float*)d_in[5];
  const float* Wv = (const float*)d_in[6];
  const float* Wo = (const float*)d_in[7];
  float* out = (float*)d_out;

  char* ws = (char*)d_ws;
  __hip_bfloat16* xb    = (__hip_bfloat16*)(ws);                       // 16 MB
  __hip_bfloat16* wqkvt = (__hip_bfloat16*)(ws + 16777216);            // 12 MB  [3072][2048]
  __hip_bfloat16* wot   = (__hip_bfloat16*)(ws + 29360128);            // 8 MB   [2048][2048]
  __hip_bfloat16* qkv   = (__hip_bfloat16*)(ws + 37748736);            // 24 MB  [4096][3072]
  __hip_bfloat16* aout  = (__hip_bfloat16*)(ws + 62914560);            // 16 MB  [4096][2048]

  dim3 tb(32, 8);
  cvt_bf16_kernel<<<8192, 256, 0, stream>>>(x, xb, 2097152);
  transpose_bf16_kernel<<<dim3(64, 64), tb, 0, stream>>>(Wq, wqkvt, 2048, 2048);
  transpose_bf16_kernel<<<dim3(16, 64), tb, 0, stream>>>(Wk, wqkvt + 2048 * 2048, 2048, 512);
  transpose_bf16_kernel<<<dim3(16, 64), tb, 0, stream>>>(Wv, wqkvt + 2560 * 2048, 2048, 512);
  transpose_bf16_kernel<<<dim3(64, 64), tb, 0, stream>>>(Wo, wot, 2048, 2048);

  gemm_bt_kernel<__hip_bfloat16><<<dim3(24, 32), 256, 0, stream>>>(xb, wqkvt, qkv, 3072, 2048);
  rope_kernel<<<20480, 256, 0, stream>>>(qkv, cosb, sinb);
  attn_kernel<<<dim3(32, 32), 256, 0, stream>>>(qkv, aout);
  gemm_bt_kernel<float><<<dim3(16, 32), 256, 0, stream>>>(aout, wot, out, 2048, 2048);
}

// Round 3
// 488.895 us; speedup vs baseline: 1.0939x; 1.0868x over previous
//
#include <hip/hip_runtime.h>
#include <hip/hip_bf16.h>
#include <cstdint>
#include <type_traits>

typedef __attribute__((ext_vector_type(8))) short short8;
typedef __attribute__((ext_vector_type(4))) float floatx4;

constexpr int S_LEN = 2048;
constexpr int QKV_N = 3072;   // q[0..2047] | k[2048..2559] | v[2560..3071]
constexpr float ATTN_SCALE = 0.08838834764831845f;  // 128^-0.5
constexpr float LOG2E = 1.4426950408889634f;

// ---------------------------------------------------------------- async G->LDS
__device__ __forceinline__ void gl_lds16(const void* gp, void* lp) {
  __builtin_amdgcn_global_load_lds(
      (__attribute__((address_space(1))) void*)(uintptr_t)gp,
      (__attribute__((address_space(3))) void*)lp,
      16, 0, 0);
}

// ------------------------------------------------ 16-lane max via DPP row_ror
__device__ __forceinline__ float rowmax16(float x) {
  union { float f; int i; } a, b;
  a.f = x;
  b.i = __builtin_amdgcn_update_dpp(0, a.i, 0x121, 0xF, 0xF, true);  // ror:1
  x = fmaxf(x, b.f); a.f = x;
  b.i = __builtin_amdgcn_update_dpp(0, a.i, 0x122, 0xF, 0xF, true);  // ror:2
  x = fmaxf(x, b.f); a.f = x;
  b.i = __builtin_amdgcn_update_dpp(0, a.i, 0x124, 0xF, 0xF, true);  // ror:4
  x = fmaxf(x, b.f); a.f = x;
  b.i = __builtin_amdgcn_update_dpp(0, a.i, 0x128, 0xF, 0xF, true);  // ror:8
  return fmaxf(x, b.f);
}

// ---------------------------------------------------------------- fp32 -> bf16
__global__ void cvt_bf16_kernel(const float* __restrict__ src,
                                __hip_bfloat16* __restrict__ dst, int n4) {
  int i = blockIdx.x * blockDim.x + threadIdx.x;
  if (i >= n4) return;
  float4 f = reinterpret_cast<const float4*>(src)[i];
  union { unsigned long long u64; __hip_bfloat16 h[4]; } u;
  u.h[0] = __float2bfloat16(f.x);
  u.h[1] = __float2bfloat16(f.y);
  u.h[2] = __float2bfloat16(f.z);
  u.h[3] = __float2bfloat16(f.w);
  reinterpret_cast<unsigned long long*>(dst)[i] = u.u64;
}

// ------------------------------------------------- fp32 [K][N] -> bf16 [N][K]
__global__ void transpose_bf16_kernel(const float* __restrict__ src,
                                      __hip_bfloat16* __restrict__ dst,
                                      int K, int N) {
  __shared__ float tile[32][33];
  int n0 = blockIdx.x * 32, k0 = blockIdx.y * 32;
  int tx = threadIdx.x, ty = threadIdx.y;   // (32, 8)
#pragma unroll
  for (int i = ty; i < 32; i += 8)
    tile[i][tx] = src[(size_t)(k0 + i) * N + n0 + tx];
  __syncthreads();
#pragma unroll
  for (int i = ty; i < 32; i += 8)
    dst[(size_t)(n0 + i) * K + k0 + tx] = __float2bfloat16(tile[tx][i]);
}

// --------------------------------------------------------------------- GEMM
// C[M][N] = A[M][K] * Bt[N][K]^T ; bf16 in, fp32 acc, OutT out.
template <typename OutT>
__global__ __launch_bounds__(256, 2) void gemm_bt_kernel(
    const __hip_bfloat16* __restrict__ A,
    const __hip_bfloat16* __restrict__ Bt,
    OutT* __restrict__ C, int N, int K) {
  __shared__ __align__(16) __hip_bfloat16 lds[2 * 128 * 64];
  const int tid = threadIdx.x;
  const int wave = tid >> 6, lane = tid & 63;
  const int quad = lane >> 4, l15 = lane & 15;
  const int wm = wave >> 1, wn = wave & 1;
  const int m0 = blockIdx.y * 128, n0 = blockIdx.x * 128;

  floatx4 acc[4][4] = {};

  const __hip_bfloat16* Ab = A + (size_t)m0 * K;
  const __hip_bfloat16* Bb = Bt + (size_t)n0 * K;
  const int i0 = wave * 4;

  for (int k0 = 0; k0 < K; k0 += 64) {
#pragma unroll
    for (int j = 0; j < 4; ++j) {
      const int i = i0 + j;
      const int kchunk = i >> 1;
      const int row = ((i & 1) << 6) | lane;
      gl_lds16(Ab + (size_t)row * K + (k0 + kchunk * 8), &lds[i * 512]);
      gl_lds16(Bb + (size_t)row * K + (k0 + kchunk * 8), &lds[8192 + i * 512]);
    }
    __syncthreads();
#pragma unroll
    for (int kk = 0; kk < 2; ++kk) {
      short8 a[4], b[4];
#pragma unroll
      for (int mi = 0; mi < 4; ++mi)
        a[mi] = *(const short8*)&lds[((((kk << 2) | quad) * 128) + wm * 64 + mi * 16 + l15) * 8];
#pragma unroll
      for (int ni = 0; ni < 4; ++ni)
        b[ni] = *(const short8*)&lds[8192 + ((((kk << 2) | quad) * 128) + wn * 64 + ni * 16 + l15) * 8];
#pragma unroll
      for (int mi = 0; mi < 4; ++mi)
#pragma unroll
        for (int ni = 0; ni < 4; ++ni)
          acc[mi][ni] = __builtin_amdgcn_mfma_f32_16x16x32_bf16(a[mi], b[ni], acc[mi][ni], 0, 0, 0);
    }
    __syncthreads();
  }

#pragma unroll
  for (int mi = 0; mi < 4; ++mi)
#pragma unroll
    for (int ni = 0; ni < 4; ++ni)
#pragma unroll
      for (int r = 0; r < 4; ++r) {
        int row = m0 + wm * 64 + mi * 16 + quad * 4 + r;
        int col = n0 + wn * 64 + ni * 16 + l15;
        float v = acc[mi][ni][r];
        if constexpr (std::is_same<OutT, float>::value)
          C[(size_t)row * N + col] = v;
        else
          C[(size_t)row * N + col] = __float2bfloat16(v);
      }
}

// --------------------------------------------------------------------- RoPE
// Vectorized: each thread does 8 consecutive d in the first half + their pairs.
__global__ void rope_kernel(__hip_bfloat16* __restrict__ qkv,
                            const float* __restrict__ cosb,
                            const float* __restrict__ sinb) {
  int t = blockIdx.x * blockDim.x + threadIdx.x;  // 4096*20*8 threads
  int c8 = t & 7;                // d0 = c8*8 in [0,64)
  int head = (t >> 3) % 20;
  int row = t / 160;
  int s = row & (S_LEN - 1);
  size_t base = (size_t)row * QKV_N + head * 128 + c8 * 8;
  short8 x0 = *(const short8*)(qkv + base);
  short8 x1 = *(const short8*)(qkv + base + 64);
  float ca[4], sa[4], cb[4], sb[4];
  *(float4*)ca = *(const float4*)&cosb[s * 64 + c8 * 4];
  *(float4*)sa = *(const float4*)&sinb[s * 64 + c8 * 4];
  *(float4*)cb = *(const float4*)&cosb[s * 64 + 32 + c8 * 4];
  *(float4*)sb = *(const float4*)&sinb[s * 64 + 32 + c8 * 4];
  short8 y0, y1;
#pragma unroll
  for (int e = 0; e < 8; ++e) {
    union { short s; __hip_bfloat16 h; } u0, u1, w0, w1;
    u0.s = x0[e]; u1.s = x1[e];
    float f0 = __bfloat162float(u0.h), f1 = __bfloat162float(u1.h);
    int j = e >> 1;
    w0.h = __float2bfloat16(f0 * ca[j] - f1 * sa[j]);
    w1.h = __float2bfloat16(f1 * cb[j] + f0 * sb[j]);
    y0[e] = w0.s; y1[e] = w1.s;
  }
  *(short8*)(qkv + base) = y0;
  *(short8*)(qkv + base + 64) = y1;
}

// ---------------------------------------------------------------- attention
// grid (32 q-tiles, 32 bh), 256 thr, wave w owns q rows qt*64+w*16..+15.
// K: double-buffered global_load_lds DMA, chunk-transposed (c = (d/8)*64+kv).
// V: double-buffered LDS [d][kv+8], register prefetch one tile ahead.
// ONE barrier per iteration: prefetch issues right after it -> true overlap.
// qt chosen complementary across co-resident blocks for CU load balance.
__global__ __launch_bounds__(256, 2) void attn_kernel(
    const __hip_bfloat16* __restrict__ qkv,   // [4096][3072]
    __hip_bfloat16* __restrict__ aout) {      // [4096][2048]
  const int bh = blockIdx.y;
  const int qt = (blockIdx.y & 16) ? blockIdx.x : (31 - blockIdx.x);
  const int b = bh >> 4, h = bh & 15;
  const int kvh = h >> 2;                     // GQA: group of 4

  __shared__ __align__(16) __hip_bfloat16 Kbuf[2][1024 * 8];  // 2 x 16 KB
  __shared__ __align__(16) __hip_bfloat16 Vbuf[2][128 * 72];  // 2 x 18 KB
  __shared__ __align__(16) __hip_bfloat16 Plds[4 * 16 * 72];  // 9 KB

  const int tid = threadIdx.x;
  const int wave = tid >> 6, lane = tid & 63;
  const int quad = lane >> 4, l15 = lane & 15;

  // Q fragments in registers for the whole KV loop (A-operand layout).
  const __hip_bfloat16* qbase = qkv + (size_t)(b * S_LEN + qt * 64) * QKV_N + h * 128;
  short8 qfrag[4];
#pragma unroll
  for (int kc = 0; kc < 4; ++kc)
    qfrag[kc] = *(const short8*)(qbase + (size_t)(wave * 16 + l15) * QKV_N + kc * 32 + quad * 8);

  const __hip_bfloat16* kvrow0 = qkv + (size_t)(b * S_LEN) * QKV_N + 2048 + kvh * 128;

  // ---- prologue: DMA K(0) -> Kbuf[0]; V(0) -> regs -> Vbuf[0]
  {
#pragma unroll
    for (int j = 0; j < 4; ++j) {
      int c = tid + 256 * j;               // chunk = (d/8)*64 + kv
      int kv = c & 63, dc = c >> 6;
      gl_lds16(kvrow0 + (size_t)kv * QKV_N + dc * 8, &Kbuf[0][c * 8]);
    }
    const __hip_bfloat16* vb = kvrow0 + 512;
#pragma unroll
    for (int j = 0; j < 2; ++j) {
      int p = tid + 256 * j;
      int kvp = (p & 31) * 2, d0 = (p >> 5) * 8;
      short8 r0 = *(const short8*)(vb + (size_t)kvp * QKV_N + d0);
      short8 r1 = *(const short8*)(vb + (size_t)(kvp + 1) * QKV_N + d0);
#pragma unroll
      for (int e = 0; e < 8; ++e) {
        unsigned int pk = (unsigned short)r0[e] | ((unsigned int)(unsigned short)r1[e] << 16);
        *(unsigned int*)&Vbuf[0][(d0 + e) * 72 + kvp] = pk;
      }
    }
  }

  float m_r[4];
  floatx4 o[8] = {};
  floatx4 o_l = {};     // running row-sum accumulator (ones-column MFMA)
#pragma unroll
  for (int r = 0; r < 4; ++r) m_r[r] = -1e30f;

  short8 onesb;
#pragma unroll
  for (int e = 0; e < 8; ++e) onesb[e] = (short)0x3F80;  // bf16 1.0

  __hip_bfloat16* pw = &Plds[wave * 16 * 72];
  const int nt = qt + 1;
  short8 vnxt[4];

  for (int kt = 0; kt < nt; ++kt) {
    const int cur = kt & 1;
    __syncthreads();   // A(kt): K(kt)/V(kt) in buf[cur] visible; drains prev DMA

    // prefetch next tile right after the barrier: a full compute phase of slack
    if (kt + 1 < nt) {
      const __hip_bfloat16* kb = kvrow0 + (size_t)(kt + 1) * 64 * QKV_N;
#pragma unroll
      for (int j = 0; j < 4; ++j) {
        int c = tid + 256 * j;
        int kv = c & 63, dc = c >> 6;
        gl_lds16(kb + (size_t)kv * QKV_N + dc * 8, &Kbuf[1 - cur][c * 8]);
      }
      const __hip_bfloat16* vb = kb + 512;
#pragma unroll
      for (int j = 0; j < 2; ++j) {
        int p = tid + 256 * j;
        int kvp = (p & 31) * 2, d0 = (p >> 5) * 8;
        vnxt[2 * j]     = *(const short8*)(vb + (size_t)kvp * QKV_N + d0);
        vnxt[2 * j + 1] = *(const short8*)(vb + (size_t)(kvp + 1) * QKV_N + d0);
      }
    }

    // scores S = Q K^T  (B-frag from chunk-transposed Kbuf: conflict-free)
    floatx4 sc[4] = {};
#pragma unroll
    for (int ni = 0; ni < 4; ++ni)
#pragma unroll
      for (int kc = 0; kc < 4; ++kc) {
        short8 bf = *(const short8*)&Kbuf[cur][((kc * 4 + quad) * 64 + ni * 16 + l15) * 8];
        sc[ni] = __builtin_amdgcn_mfma_f32_16x16x32_bf16(qfrag[kc], bf, sc[ni], 0, 0, 0);
      }

    const int qrow = qt * 64 + wave * 16 + quad * 4;
    if (kt == qt) {
#pragma unroll
      for (int ni = 0; ni < 4; ++ni) {
        int kvcol = kt * 64 + ni * 16 + l15;
#pragma unroll
        for (int r = 0; r < 4; ++r) {
          float s = sc[ni][r] * ATTN_SCALE;
          sc[ni][r] = (kvcol > qrow + r) ? -1e30f : s;
        }
      }
    } else {
#pragma unroll
      for (int ni = 0; ni < 4; ++ni)
#pragma unroll
        for (int r = 0; r < 4; ++r) sc[ni][r] *= ATTN_SCALE;
    }

    // online softmax: row max via DPP rotations (VALU, no DS pipe)
    float alpha[4];
#pragma unroll
    for (int r = 0; r < 4; ++r) {
      float v = fmaxf(fmaxf(sc[0][r], sc[1][r]), fmaxf(sc[2][r], sc[3][r]));
      v = rowmax16(v);
      float mnew = fmaxf(m_r[r], v);
      alpha[r] = exp2f((m_r[r] - mnew) * LOG2E);
      m_r[r] = mnew;
#pragma unroll
      for (int ni = 0; ni < 4; ++ni) {
        float p = exp2f((sc[ni][r] - mnew) * LOG2E);
        pw[(quad * 4 + r) * 72 + ni * 16 + l15] = __float2bfloat16(p);
      }
    }

#pragma unroll
    for (int nc = 0; nc < 8; ++nc)
#pragma unroll
      for (int r = 0; r < 4; ++r) o[nc][r] *= alpha[r];
#pragma unroll
    for (int r = 0; r < 4; ++r) o_l[r] *= alpha[r];

    // O += P V ; l += P 1   (A = P from LDS round-trip; B = V^T tile)
#pragma unroll
    for (int kk2 = 0; kk2 < 2; ++kk2) {
      short8 pa = *(const short8*)&pw[l15 * 72 + kk2 * 32 + quad * 8];
#pragma unroll
      for (int nc = 0; nc < 8; ++nc) {
        short8 vb = *(const short8*)&Vbuf[cur][(nc * 16 + l15) * 72 + kk2 * 32 + quad * 8];
        o[nc] = __builtin_amdgcn_mfma_f32_16x16x32_bf16(pa, vb, o[nc], 0, 0, 0);
      }
      o_l = __builtin_amdgcn_mfma_f32_16x16x32_bf16(pa, onesb, o_l, 0, 0, 0);
    }

    // V(kt+1): regs -> other LDS buffer (readers wait at next barrier)
    if (kt + 1 < nt) {
#pragma unroll
      for (int j = 0; j < 2; ++j) {
        int p = tid + 256 * j;
        int kvp = (p & 31) * 2, d0 = (p >> 5) * 8;
        short8 r0 = vnxt[2 * j], r1 = vnxt[2 * j + 1];
#pragma unroll
        for (int e = 0; e < 8; ++e) {
          unsigned int pk = (unsigned short)r0[e] | ((unsigned int)(unsigned short)r1[e] << 16);
          *(unsigned int*)&Vbuf[1 - cur][(d0 + e) * 72 + kvp] = pk;
        }
      }
    }
  }

  float inv[4];
#pragma unroll
  for (int r = 0; r < 4; ++r) inv[r] = 1.0f / o_l[r];
  const size_t orow0 = (size_t)(b * S_LEN + qt * 64 + wave * 16 + quad * 4);
#pragma unroll
  for (int nc = 0; nc < 8; ++nc)
#pragma unroll
    for (int r = 0; r < 4; ++r)
      aout[(orow0 + r) * 2048 + h * 128 + nc * 16 + l15] =
          __float2bfloat16(o[nc][r] * inv[r]);
}

// -------------------------------------------------------------------- launch
extern "C" void kernel_launch(void* const* d_in, const int* in_sizes, int n_in,
                              void* d_out, int out_size, void* d_ws, size_t ws_size,
                              hipStream_t stream) {
  const float* x    = (const float*)d_in[0];
  const float* cosb = (const float*)d_in[1];
  const float* sinb = (const float*)d_in[2];
  // d_in[3] = mask (causal, implemented analytically)
  const float* Wq = (const float*)d_in[4];
  const float* Wk = (const float*)d_in[5];
  const float* Wv = (const float*)d_in[6];
  const float* Wo = (const float*)d_in[7];
  float* out = (float*)d_out;

  char* ws = (char*)d_ws;
  __hip_bfloat16* xb    = (__hip_bfloat16*)(ws);                       // 16 MB
  __hip_bfloat16* wqkvt = (__hip_bfloat16*)(ws + 16777216);            // 12 MB  [3072][2048]
  __hip_bfloat16* wot   = (__hip_bfloat16*)(ws + 29360128);            // 8 MB   [2048][2048]
  __hip_bfloat16* qkv   = (__hip_bfloat16*)(ws + 37748736);            // 24 MB  [4096][3072]
  __hip_bfloat16* aout  = (__hip_bfloat16*)(ws + 62914560);            // 16 MB  [4096][2048]

  dim3 tb(32, 8);
  cvt_bf16_kernel<<<8192, 256, 0, stream>>>(x, xb, 2097152);
  transpose_bf16_kernel<<<dim3(64, 64), tb, 0, stream>>>(Wq, wqkvt, 2048, 2048);
  transpose_bf16_kernel<<<dim3(16, 64), tb, 0, stream>>>(Wk, wqkvt + 2048 * 2048, 2048, 512);
  transpose_bf16_kernel<<<dim3(16, 64), tb, 0, stream>>>(Wv, wqkvt + 2560 * 2048, 2048, 512);
  transpose_bf16_kernel<<<dim3(64, 64), tb, 0, stream>>>(Wo, wot, 2048, 2048);

  gemm_bt_kernel<__hip_bfloat16><<<dim3(24, 32), 256, 0, stream>>>(xb, wqkvt, qkv, 3072, 2048);
  rope_kernel<<<2560, 256, 0, stream>>>(qkv, cosb, sinb);
  attn_kernel<<<dim3(32, 32), 256, 0, stream>>>(qkv, aout);
  gemm_bt_kernel<float><<<dim3(16, 32), 256, 0, stream>>>(aout, wot, out, 2048, 2048);
}

// Round 4
// 435.136 us; speedup vs baseline: 1.2291x; 1.1235x over previous
//
#include <hip/hip_runtime.h>
#include <hip/hip_bf16.h>
#include <cstdint>
#include <type_traits>

typedef __attribute__((ext_vector_type(8))) short short8;
typedef __attribute__((ext_vector_type(4))) float floatx4;

constexpr int S_LEN = 2048;
constexpr float ATTN_SCALE = 0.08838834764831845f;  // 128^-0.5
constexpr float LOG2E = 1.4426950408889634f;
constexpr float CP = ATTN_SCALE * LOG2E;            // fold scale into exp2 arg

// ---------------------------------------------------------------- async G->LDS
__device__ __forceinline__ void gl_lds16(const void* gp, void* lp) {
  __builtin_amdgcn_global_load_lds(
      (__attribute__((address_space(1))) void*)(uintptr_t)gp,
      (__attribute__((address_space(3))) void*)lp,
      16, 0, 0);
}

// ------------------------------------------------ 16-lane max via DPP row_ror
__device__ __forceinline__ float rowmax16(float x) {
  union { float f; int i; } a, b;
  a.f = x;
  b.i = __builtin_amdgcn_update_dpp(0, a.i, 0x121, 0xF, 0xF, true);  // ror:1
  x = fmaxf(x, b.f); a.f = x;
  b.i = __builtin_amdgcn_update_dpp(0, a.i, 0x122, 0xF, 0xF, true);  // ror:2
  x = fmaxf(x, b.f); a.f = x;
  b.i = __builtin_amdgcn_update_dpp(0, a.i, 0x124, 0xF, 0xF, true);  // ror:4
  x = fmaxf(x, b.f); a.f = x;
  b.i = __builtin_amdgcn_update_dpp(0, a.i, 0x128, 0xF, 0xF, true);  // ror:8
  return fmaxf(x, b.f);
}

// ---------------------------------------------------------------- fp32 -> bf16
__global__ void cvt_bf16_kernel(const float* __restrict__ src,
                                __hip_bfloat16* __restrict__ dst, int n4) {
  int i = blockIdx.x * blockDim.x + threadIdx.x;
  if (i >= n4) return;
  float4 f = reinterpret_cast<const float4*>(src)[i];
  union { unsigned long long u64; __hip_bfloat16 h[4]; } u;
  u.h[0] = __float2bfloat16(f.x);
  u.h[1] = __float2bfloat16(f.y);
  u.h[2] = __float2bfloat16(f.z);
  u.h[3] = __float2bfloat16(f.w);
  reinterpret_cast<unsigned long long*>(dst)[i] = u.u64;
}

// ------------------------------------------------- fp32 [K][N] -> bf16 [N][K]
__global__ void transpose_bf16_kernel(const float* __restrict__ src,
                                      __hip_bfloat16* __restrict__ dst,
                                      int K, int N) {
  __shared__ float tile[32][33];
  int n0 = blockIdx.x * 32, k0 = blockIdx.y * 32;
  int tx = threadIdx.x, ty = threadIdx.y;   // (32, 8)
#pragma unroll
  for (int i = ty; i < 32; i += 8)
    tile[i][tx] = src[(size_t)(k0 + i) * N + n0 + tx];
  __syncthreads();
#pragma unroll
  for (int i = ty; i < 32; i += 8)
    dst[(size_t)(n0 + i) * K + k0 + tx] = __float2bfloat16(tile[tx][i]);
}

// ------------------------------------------------------------ QKV GEMM (fused)
// C = xb[4096][2048] @ wqkvt[3072][2048]^T, written to attention-native layouts:
//   cols 0..2047    -> qbuf[row][col]                         (row-major)
//   cols 2048..2559 -> kbuf tiles, chunk-transposed:  tile=((b*4+kvh)*32+kt)
//                      elem (kv,d) at tile*8192 + (d>>3)*512 + kv*8 + (d&7)
//   cols 2560..3071 -> vbuf tiles, V^T XOR-swizzled:
//                      elem (kv,d) at tile*8192 + d*64 + (kv ^ ((d&7)<<3))
__global__ __launch_bounds__(256, 2) void qkv_gemm_kernel(
    const __hip_bfloat16* __restrict__ A,
    const __hip_bfloat16* __restrict__ Bt,
    __hip_bfloat16* __restrict__ qbuf,
    __hip_bfloat16* __restrict__ kbuf,
    __hip_bfloat16* __restrict__ vbuf) {
  constexpr int K = 2048;
  __shared__ __align__(16) __hip_bfloat16 lds[2 * 128 * 64];
  const int tid = threadIdx.x;
  const int wave = tid >> 6, lane = tid & 63;
  const int quad = lane >> 4, l15 = lane & 15;
  const int wm = wave >> 1, wn = wave & 1;
  const int m0 = blockIdx.y * 128, n0 = blockIdx.x * 128;

  floatx4 acc[4][4] = {};
  const __hip_bfloat16* Ab = A + (size_t)m0 * K;
  const __hip_bfloat16* Bb = Bt + (size_t)n0 * K;
  const int i0 = wave * 4;

  for (int k0 = 0; k0 < K; k0 += 64) {
#pragma unroll
    for (int j = 0; j < 4; ++j) {
      const int i = i0 + j;
      const int kchunk = i >> 1;
      const int row = ((i & 1) << 6) | lane;
      gl_lds16(Ab + (size_t)row * K + (k0 + kchunk * 8), &lds[i * 512]);
      gl_lds16(Bb + (size_t)row * K + (k0 + kchunk * 8), &lds[8192 + i * 512]);
    }
    __syncthreads();
#pragma unroll
    for (int kk = 0; kk < 2; ++kk) {
      short8 a[4], b[4];
#pragma unroll
      for (int mi = 0; mi < 4; ++mi)
        a[mi] = *(const short8*)&lds[((((kk << 2) | quad) * 128) + wm * 64 + mi * 16 + l15) * 8];
#pragma unroll
      for (int ni = 0; ni < 4; ++ni)
        b[ni] = *(const short8*)&lds[8192 + ((((kk << 2) | quad) * 128) + wn * 64 + ni * 16 + l15) * 8];
#pragma unroll
      for (int mi = 0; mi < 4; ++mi)
#pragma unroll
        for (int ni = 0; ni < 4; ++ni)
          acc[mi][ni] = __builtin_amdgcn_mfma_f32_16x16x32_bf16(a[mi], b[ni], acc[mi][ni], 0, 0, 0);
    }
    __syncthreads();
  }

  const int region = (n0 - 2048) >> 7;          // valid when n0 >= 2048
  const int kvh = region & 3;
#pragma unroll
  for (int mi = 0; mi < 4; ++mi)
#pragma unroll
    for (int ni = 0; ni < 4; ++ni)
#pragma unroll
      for (int r = 0; r < 4; ++r) {
        int row = m0 + wm * 64 + mi * 16 + quad * 4 + r;
        int col = n0 + wn * 64 + ni * 16 + l15;
        __hip_bfloat16 val = __float2bfloat16(acc[mi][ni][r]);
        if (n0 < 2048) {
          qbuf[(size_t)row * 2048 + col] = val;
        } else {
          int d = wn * 64 + ni * 16 + l15;      // 0..127 within the head
          int s = row & (S_LEN - 1), bb = row >> 11;
          size_t tb = ((size_t)(bb * 4 + kvh) * 32 + (s >> 6)) * 8192;
          int kv = s & 63;
          if (region < 4)
            kbuf[tb + ((d >> 3) << 9) + (kv << 3) + (d & 7)] = val;
          else
            vbuf[tb + d * 64 + (kv ^ ((d & 7) << 3))] = val;
        }
      }
}

// --------------------------------------------------------------- AO GEMM
__global__ __launch_bounds__(256, 2) void gemm_bt_f32_kernel(
    const __hip_bfloat16* __restrict__ A,
    const __hip_bfloat16* __restrict__ Bt,
    float* __restrict__ C, int N, int K) {
  __shared__ __align__(16) __hip_bfloat16 lds[2 * 128 * 64];
  const int tid = threadIdx.x;
  const int wave = tid >> 6, lane = tid & 63;
  const int quad = lane >> 4, l15 = lane & 15;
  const int wm = wave >> 1, wn = wave & 1;
  const int m0 = blockIdx.y * 128, n0 = blockIdx.x * 128;

  floatx4 acc[4][4] = {};
  const __hip_bfloat16* Ab = A + (size_t)m0 * K;
  const __hip_bfloat16* Bb = Bt + (size_t)n0 * K;
  const int i0 = wave * 4;

  for (int k0 = 0; k0 < K; k0 += 64) {
#pragma unroll
    for (int j = 0; j < 4; ++j) {
      const int i = i0 + j;
      const int kchunk = i >> 1;
      const int row = ((i & 1) << 6) | lane;
      gl_lds16(Ab + (size_t)row * K + (k0 + kchunk * 8), &lds[i * 512]);
      gl_lds16(Bb + (size_t)row * K + (k0 + kchunk * 8), &lds[8192 + i * 512]);
    }
    __syncthreads();
#pragma unroll
    for (int kk = 0; kk < 2; ++kk) {
      short8 a[4], b[4];
#pragma unroll
      for (int mi = 0; mi < 4; ++mi)
        a[mi] = *(const short8*)&lds[((((kk << 2) | quad) * 128) + wm * 64 + mi * 16 + l15) * 8];
#pragma unroll
      for (int ni = 0; ni < 4; ++ni)
        b[ni] = *(const short8*)&lds[8192 + ((((kk << 2) | quad) * 128) + wn * 64 + ni * 16 + l15) * 8];
#pragma unroll
      for (int mi = 0; mi < 4; ++mi)
#pragma unroll
        for (int ni = 0; ni < 4; ++ni)
          acc[mi][ni] = __builtin_amdgcn_mfma_f32_16x16x32_bf16(a[mi], b[ni], acc[mi][ni], 0, 0, 0);
    }
    __syncthreads();
  }

#pragma unroll
  for (int mi = 0; mi < 4; ++mi)
#pragma unroll
    for (int ni = 0; ni < 4; ++ni)
#pragma unroll
      for (int r = 0; r < 4; ++r) {
        int row = m0 + wm * 64 + mi * 16 + quad * 4 + r;
        int col = n0 + wn * 64 + ni * 16 + l15;
        C[(size_t)row * N + col] = acc[mi][ni][r];
      }
}

// --------------------------------------------------------------------- RoPE
// out[d] = x[d]*cos[d>>1] - x[d+64]*sin[d>>1];  out[d+64] = x[d+64]*cos[32+(d>>1)] + x[d]*sin[32+(d>>1)]
__device__ __forceinline__ void rope8(short8 x0, short8 x1, const float* ca,
                                      const float* sa, const float* cb,
                                      const float* sb, short8& y0, short8& y1) {
#pragma unroll
  for (int e = 0; e < 8; ++e) {
    union { short s; __hip_bfloat16 h; } u0, u1, w0, w1;
    u0.s = x0[e]; u1.s = x1[e];
    float f0 = __bfloat162float(u0.h), f1 = __bfloat162float(u1.h);
    int j = e >> 1;
    w0.h = __float2bfloat16(f0 * ca[j] - f1 * sa[j]);
    w1.h = __float2bfloat16(f1 * cb[j] + f0 * sb[j]);
    y0[e] = w0.s; y1[e] = w1.s;
  }
}

__global__ void rope_q_kernel(__hip_bfloat16* __restrict__ qbuf,
                              const float* __restrict__ cosb,
                              const float* __restrict__ sinb) {
  int t = blockIdx.x * blockDim.x + threadIdx.x;   // 4096*16*8 threads
  int c8 = t & 7;
  int head = (t >> 3) & 15;
  int row = t >> 7;
  int s = row & (S_LEN - 1);
  size_t base = (size_t)row * 2048 + head * 128 + c8 * 8;
  short8 x0 = *(const short8*)(qbuf + base);
  short8 x1 = *(const short8*)(qbuf + base + 64);
  float ca[4], sa[4], cb[4], sb[4];
  *(float4*)ca = *(const float4*)&cosb[s * 64 + c8 * 4];
  *(float4*)sa = *(const float4*)&sinb[s * 64 + c8 * 4];
  *(float4*)cb = *(const float4*)&cosb[s * 64 + 32 + c8 * 4];
  *(float4*)sb = *(const float4*)&sinb[s * 64 + 32 + c8 * 4];
  short8 y0, y1;
  rope8(x0, x1, ca, sa, cb, sb, y0, y1);
  *(short8*)(qbuf + base) = y0;
  *(short8*)(qbuf + base + 64) = y1;
}

// K in chunk-transposed tiles: elem (kv,d) at tile*8192 + (d>>3)*512 + kv*8 + (d&7)
// pair (d, d+64) -> +4096 elems; 8 consecutive d (fixed c8=d>>3) are contiguous.
__global__ void rope_k_kernel(__hip_bfloat16* __restrict__ kbuf,
                              const float* __restrict__ cosb,
                              const float* __restrict__ sinb) {
  int t = blockIdx.x * blockDim.x + threadIdx.x;   // 8*32*64*8 threads
  int c8 = t & 7;
  int kv = (t >> 3) & 63;
  int tile = t >> 9;                               // (b*4+kvh)*32 + kt
  int s = (tile & 31) * 64 + kv;
  size_t a0 = (size_t)tile * 8192 + c8 * 512 + kv * 8;
  short8 x0 = *(const short8*)(kbuf + a0);
  short8 x1 = *(const short8*)(kbuf + a0 + 4096);
  float ca[4], sa[4], cb[4], sb[4];
  *(float4*)ca = *(const float4*)&cosb[s * 64 + c8 * 4];
  *(float4*)sa = *(const float4*)&sinb[s * 64 + c8 * 4];
  *(float4*)cb = *(const float4*)&cosb[s * 64 + 32 + c8 * 4];
  *(float4*)sb = *(const float4*)&sinb[s * 64 + 32 + c8 * 4];
  short8 y0, y1;
  rope8(x0, x1, ca, sa, cb, sb, y0, y1);
  *(short8*)(kbuf + a0) = y0;
  *(short8*)(kbuf + a0 + 4096) = y1;
}

// ---------------------------------------------------------------- attention
// grid (16, 32), 256 thr. Block = 128 q-rows (2 rowsets of 64) x one head.
// K,V: double-buffered coalesced global_load_lds DMA from attention-native
// global layouts (K chunk-transposed, V transposed+XOR-swizzled).
// One barrier per KV tile; softmax scale folded into exp2 arg.
__global__ __launch_bounds__(256, 2) void attn_kernel(
    const __hip_bfloat16* __restrict__ qbuf,   // [4096][2048]
    const __hip_bfloat16* __restrict__ kbuf,   // tiles
    const __hip_bfloat16* __restrict__ vbuf,   // tiles
    __hip_bfloat16* __restrict__ aout) {       // [4096][2048]
  const int qt = (blockIdx.y & 16) ? blockIdx.x : (15 - blockIdx.x);  // 128-row
  const int bh = blockIdx.y;
  const int b = bh >> 4, h = bh & 15;
  const int kvh = h >> 2;

  __shared__ __align__(16) __hip_bfloat16 Kbuf[2][8192];  // 2 x 16 KB
  __shared__ __align__(16) __hip_bfloat16 Vbuf[2][8192];  // 2 x 16 KB
  __shared__ __align__(16) __hip_bfloat16 Plds[4 * 16 * 72];  // 9 KB

  const int tid = threadIdx.x;
  const int wave = tid >> 6, lane = tid & 63;
  const int quad = lane >> 4, l15 = lane & 15;

  // Q fragments (A-operand layout), rowset rs rows = qt*128 + rs*64 + wave*16 + l15
  short8 qfrag[2][4];
#pragma unroll
  for (int rs = 0; rs < 2; ++rs)
#pragma unroll
    for (int kc = 0; kc < 4; ++kc)
      qfrag[rs][kc] = *(const short8*)(qbuf +
          (size_t)(b * S_LEN + qt * 128 + rs * 64 + wave * 16 + l15) * 2048 +
          h * 128 + kc * 32 + quad * 8);

  const __hip_bfloat16* ktiles = kbuf + (size_t)(b * 4 + kvh) * 32 * 8192;
  const __hip_bfloat16* vtiles = vbuf + (size_t)(b * 4 + kvh) * 32 * 8192;
  const int nt = 2 * qt + 2;

  // prologue: DMA K(0), V(0) into buf 0 — coalesced (lane-contiguous chunks)
#pragma unroll
  for (int j = 0; j < 4; ++j) {
    int c = tid + 256 * j;
    gl_lds16(ktiles + c * 8, &Kbuf[0][c * 8]);
    gl_lds16(vtiles + c * 8, &Vbuf[0][c * 8]);
  }

  float m_r[2][4];
  floatx4 o[2][8] = {};
  floatx4 o_l[2] = {};
#pragma unroll
  for (int rs = 0; rs < 2; ++rs)
#pragma unroll
    for (int r = 0; r < 4; ++r) m_r[rs][r] = -1e30f;

  short8 onesb;
#pragma unroll
  for (int e = 0; e < 8; ++e) onesb[e] = (short)0x3F80;  // bf16 1.0

  __hip_bfloat16* pw = &Plds[wave * 16 * 72];

  for (int kt = 0; kt < nt; ++kt) {
    const int cur = kt & 1;
    __syncthreads();   // K(kt)/V(kt) DMA drained & visible

    if (kt + 1 < nt) {
      const __hip_bfloat16* kb = ktiles + (size_t)(kt + 1) * 8192;
      const __hip_bfloat16* vb = vtiles + (size_t)(kt + 1) * 8192;
#pragma unroll
      for (int j = 0; j < 4; ++j) {
        int c = tid + 256 * j;
        gl_lds16(kb + c * 8, &Kbuf[1 - cur][c * 8]);
        gl_lds16(vb + c * 8, &Vbuf[1 - cur][c * 8]);
      }
    }

    // S = Q K^T for both rowsets (K frags loaded once, used twice)
    floatx4 sc[2][4] = {};
#pragma unroll
    for (int ni = 0; ni < 4; ++ni)
#pragma unroll
      for (int kc = 0; kc < 4; ++kc) {
        short8 bf = *(const short8*)&Kbuf[cur][((kc * 4 + quad) * 64 + ni * 16 + l15) * 8];
        sc[0][ni] = __builtin_amdgcn_mfma_f32_16x16x32_bf16(qfrag[0][kc], bf, sc[0][ni], 0, 0, 0);
        sc[1][ni] = __builtin_amdgcn_mfma_f32_16x16x32_bf16(qfrag[1][kc], bf, sc[1][ni], 0, 0, 0);
      }

#pragma unroll
    for (int rs = 0; rs < 2; ++rs) {
      const int qt64 = 2 * qt + rs;
      if (kt > qt64) continue;          // rowset done (uniform branch)
      if (kt == qt64) {                 // diagonal tile: causal mask (raw units)
        const int qrow = qt * 128 + rs * 64 + wave * 16 + quad * 4;
#pragma unroll
        for (int ni = 0; ni < 4; ++ni) {
          int kvcol = kt * 64 + ni * 16 + l15;
#pragma unroll
          for (int r = 0; r < 4; ++r)
            if (kvcol > qrow + r) sc[rs][ni][r] = -1e30f;
        }
      }

      // online softmax (raw-unit max; scale folded into exp2 args via CP)
      float alpha[4];
#pragma unroll
      for (int r = 0; r < 4; ++r) {
        float v = fmaxf(fmaxf(sc[rs][0][r], sc[rs][1][r]),
                        fmaxf(sc[rs][2][r], sc[rs][3][r]));
        v = rowmax16(v);
        float mnew = fmaxf(m_r[rs][r], v);
        alpha[r] = exp2f((m_r[rs][r] - mnew) * CP);
        m_r[rs][r] = mnew;
        float mc = mnew * CP;
#pragma unroll
        for (int ni = 0; ni < 4; ++ni) {
          float p = exp2f(sc[rs][ni][r] * CP - mc);
          pw[(quad * 4 + r) * 72 + ni * 16 + l15] = __float2bfloat16(p);
        }
      }

#pragma unroll
      for (int nc = 0; nc < 8; ++nc)
#pragma unroll
        for (int r = 0; r < 4; ++r) o[rs][nc][r] *= alpha[r];
#pragma unroll
      for (int r = 0; r < 4; ++r) o_l[rs][r] *= alpha[r];

      // O += P V ; l += P 1  (P round-trip through this wave's LDS slice;
      // same-wave DS ordering makes the region safely reusable across rowsets)
#pragma unroll
      for (int kk2 = 0; kk2 < 2; ++kk2) {
        short8 pa = *(const short8*)&pw[l15 * 72 + kk2 * 32 + quad * 8];
#pragma unroll
        for (int nc = 0; nc < 8; ++nc) {
          int d = nc * 16 + l15;
          int swcol = (kk2 * 32 + quad * 8) ^ ((d & 7) << 3);
          short8 vv = *(const short8*)&Vbuf[cur][d * 64 + swcol];
          o[rs][nc] = __builtin_amdgcn_mfma_f32_16x16x32_bf16(pa, vv, o[rs][nc], 0, 0, 0);
        }
        o_l[rs] = __builtin_amdgcn_mfma_f32_16x16x32_bf16(pa, onesb, o_l[rs], 0, 0, 0);
      }
    }
  }

#pragma unroll
  for (int rs = 0; rs < 2; ++rs) {
    float inv[4];
#pragma unroll
    for (int r = 0; r < 4; ++r) inv[r] = 1.0f / o_l[rs][r];
    const size_t orow0 = (size_t)(b * S_LEN + qt * 128 + rs * 64 + wave * 16 + quad * 4);
#pragma unroll
    for (int nc = 0; nc < 8; ++nc)
#pragma unroll
      for (int r = 0; r < 4; ++r)
        aout[(orow0 + r) * 2048 + h * 128 + nc * 16 + l15] =
            __float2bfloat16(o[rs][nc][r] * inv[r]);
  }
}

// -------------------------------------------------------------------- launch
extern "C" void kernel_launch(void* const* d_in, const int* in_sizes, int n_in,
                              void* d_out, int out_size, void* d_ws, size_t ws_size,
                              hipStream_t stream) {
  const float* x    = (const float*)d_in[0];
  const float* cosb = (const float*)d_in[1];
  const float* sinb = (const float*)d_in[2];
  // d_in[3] = mask (causal, analytic)
  const float* Wq = (const float*)d_in[4];
  const float* Wk = (const float*)d_in[5];
  const float* Wv = (const float*)d_in[6];
  const float* Wo = (const float*)d_in[7];
  float* out = (float*)d_out;

  char* ws = (char*)d_ws;
  __hip_bfloat16* xb    = (__hip_bfloat16*)(ws);                 // 16 MB
  __hip_bfloat16* wqkvt = (__hip_bfloat16*)(ws + (16u << 20));   // 12 MB [3072][2048]
  __hip_bfloat16* wot   = (__hip_bfloat16*)(ws + (28u << 20));   // 8 MB  [2048][2048]
  __hip_bfloat16* qbuf  = (__hip_bfloat16*)(ws + (36u << 20));   // 16 MB [4096][2048]
  __hip_bfloat16* kbuf  = (__hip_bfloat16*)(ws + (52u << 20));   // 4 MB  tiles
  __hip_bfloat16* vbuf  = (__hip_bfloat16*)(ws + (56u << 20));   // 4 MB  tiles
  __hip_bfloat16* aout  = (__hip_bfloat16*)(ws + (60u << 20));   // 16 MB [4096][2048]

  dim3 tb(32, 8);
  cvt_bf16_kernel<<<8192, 256, 0, stream>>>(x, xb, 2097152);
  transpose_bf16_kernel<<<dim3(64, 64), tb, 0, stream>>>(Wq, wqkvt, 2048, 2048);
  transpose_bf16_kernel<<<dim3(16, 64), tb, 0, stream>>>(Wk, wqkvt + 2048 * 2048, 2048, 512);
  transpose_bf16_kernel<<<dim3(16, 64), tb, 0, stream>>>(Wv, wqkvt + 2560 * 2048, 2048, 512);
  transpose_bf16_kernel<<<dim3(64, 64), tb, 0, stream>>>(Wo, wot, 2048, 2048);

  qkv_gemm_kernel<<<dim3(24, 32), 256, 0, stream>>>(xb, wqkvt, qbuf, kbuf, vbuf);
  rope_q_kernel<<<2048, 256, 0, stream>>>(qbuf, cosb, sinb);
  rope_k_kernel<<<512, 256, 0, stream>>>(kbuf, cosb, sinb);
  attn_kernel<<<dim3(16, 32), 256, 0, stream>>>(qbuf, kbuf, vbuf, aout);
  gemm_bt_f32_kernel<<<dim3(16, 32), 256, 0, stream>>>(aout, wot, out, 2048, 2048);
}